// Round 6
// baseline (107.353 us; speedup 1.0000x reference)
//
#include <hip/hip_runtime.h>
#include <hip/hip_bf16.h>

// ZDecoder: qs[b,c,o] = MLP(concat(V(c), phi(b)))
// R5 post-mortem: pipes idle, occupancy 1.88%, write BW 1.9 TB/s vs fill 6.6 —
// limiter = write-stream locality (blocks wrote 8KiB chunks at 512KiB stride).
// R6: block = (1 batch) x (1024 combos) -> each block writes ONE contiguous,
// ascending 128 KiB region (fill-like). A[c] = A01[c&63] + Bt2[mt&7] + Bt3[r3]:
// A01 (64x64, swizzled) read once to regs; Bt2/Bt3 added per 64-combo step via
// conflict-free broadcast LDS reads; P[b] in registers. Layers 2/3 as R5
// (operand-swapped MFMA K32 + K16 from registers, no main-loop LDS writes).

typedef __attribute__((ext_vector_type(8))) short bf16x8;
typedef __attribute__((ext_vector_type(4))) short bf16x4;
typedef __attribute__((ext_vector_type(4))) float f32x4;

#define MFMA_K32(a, b, c) __builtin_amdgcn_mfma_f32_16x16x32_bf16(a, b, c, 0, 0, 0)

#if defined(__has_builtin)
#if __has_builtin(__builtin_amdgcn_mfma_f32_16x16x16bf16_1k)
#define MFMA_K16(a, b, c) __builtin_amdgcn_mfma_f32_16x16x16bf16_1k(a, b, c, 0, 0, 0)
#elif __has_builtin(__builtin_amdgcn_mfma_f32_16x16x16_bf16)
#define MFMA_K16(a, b, c) __builtin_amdgcn_mfma_f32_16x16x16_bf16(a, b, c, 0, 0, 0)
#endif
#endif
#ifndef MFMA_K16
__device__ __forceinline__ f32x4 mfma_k16_asm(bf16x4 a, bf16x4 b, f32x4 c) {
    f32x4 d;
    asm("v_mfma_f32_16x16x16_bf16 %0, %1, %2, %3" : "=v"(d) : "v"(a), "v"(b), "v"(c));
    return d;
}
#define MFMA_K16(a, b, c) mfma_k16_asm(a, b, c)
#endif

__device__ __forceinline__ short f2bf(float x) {
    union { __hip_bfloat16 b; short s; } u;
    u.b = __float2bfloat16(x);
    return u.s;
}

__device__ __forceinline__ float4 ldg4(const float* p) {
    return *reinterpret_cast<const float4*>(p);
}

__global__ __launch_bounds__(256, 4)
void zdec_kernel(const float* __restrict__ phi, const float* __restrict__ rp,
                 const float* __restrict__ w1, const float* __restrict__ b1,
                 const float* __restrict__ w2, const float* __restrict__ b2,
                 const float* __restrict__ w3, const float* __restrict__ b3,
                 float* __restrict__ out)
{
    // 24.25 KiB: A01[4096] | Bt[2048] | Pt[64]
    __shared__ float smem[6208];
    float* const A01 = smem;          // [64 low-combos][64 h], XOR-swizzled
    float* const Bt  = smem + 4096;   // [4 lv][8 rg][64 h]
    float* const Pt  = smem + 6144;   // [64 h] for this block's single batch

    const int t   = threadIdx.x;
    const int b   = blockIdx.x >> 2;  // batch 0..255
    const int cbi = blockIdx.x & 3;   // combo quarter: combos [cbi*1024, +1024)

    // ---------------- setup: B table ----------------
    {
        const int l = t >> 6, h = t & 63;
        float ws[16];
#pragma unroll
        for (int z4 = 0; z4 < 4; ++z4) {
            const float4 v = ldg4(w1 + h * 128 + l * 16 + z4 * 4);
            ws[z4*4+0] = v.x; ws[z4*4+1] = v.y; ws[z4*4+2] = v.z; ws[z4*4+3] = v.w;
        }
#pragma unroll
        for (int r = 0; r < 8; ++r) {
            float acc = 0.f;
#pragma unroll
            for (int z4 = 0; z4 < 4; ++z4) {
                const float4 v = ldg4(rp + (l * 8 + r) * 16 + z4 * 4);
                acc += ws[z4*4+0]*v.x + ws[z4*4+1]*v.y + ws[z4*4+2]*v.z + ws[z4*4+3]*v.w;
            }
            Bt[(l * 8 + r) * 64 + h] = acc;
        }
    }
    // ---------------- setup: P row for this block's batch ----------------
    if (t < 64) {
        const int h = t;
        float acc = b1[h];
#pragma unroll
        for (int p4 = 0; p4 < 16; ++p4) {
            const float4 wv = ldg4(w1 + h * 128 + 64 + p4 * 4);
            const float4 pv = ldg4(phi + b * 64 + p4 * 4);
            acc += wv.x * pv.x + wv.y * pv.y + wv.z * pv.z + wv.w * pv.w;
        }
        Pt[h] = acc;
    }
    __syncthreads();
    // ---------------- setup: A01 = Bt0[r0] + Bt1[r1], swizzled ----------------
    {
        const int h = t & 63, cg = t >> 6;
#pragma unroll
        for (int cc2 = 0; cc2 < 16; ++cc2) {
            const int cc = cg * 16 + cc2;
            A01[cc * 64 + (h ^ ((cc & 15) << 2))] =
                Bt[(cc & 7) * 64 + h] + Bt[(8 + ((cc >> 3) & 7)) * 64 + h];
        }
    }
    __syncthreads();

    // ---------------- main: 16 steps x 64 combos (contiguous ascending) -------
    const int lane = t & 63;
    const int wid  = t >> 6;
    const int q = lane >> 4;         // quarter-wave group
    const int s = lane & 15;
    const int row = (wid << 4) + s;  // lane's low-combo index (fixed all steps)
    const int amask = s << 2;

    // w2 as layer-2 A-operand: A[m=g=nt*16+s][k=h=kt*32+q*8+j]
    bf16x8 w2f[4][2];
#pragma unroll
    for (int nt = 0; nt < 4; ++nt)
#pragma unroll
        for (int kt = 0; kt < 2; ++kt) {
            const float* src = w2 + (nt * 16 + s) * 64 + kt * 32 + q * 8;
            const float4 v0 = ldg4(src), v1 = ldg4(src + 4);
            bf16x8 f;
            f[0]=f2bf(v0.x); f[1]=f2bf(v0.y); f[2]=f2bf(v0.z); f[3]=f2bf(v0.w);
            f[4]=f2bf(v1.x); f[5]=f2bf(v1.y); f[6]=f2bf(v1.z); f[7]=f2bf(v1.w);
            w2f[nt][kt] = f;
        }
    // w3 as layer-3 K=16 A-operand: A[m=o=nt3*16+s][k=g=nt*16+q*4+j]
    bf16x4 w3f[2][4];
#pragma unroll
    for (int nt3 = 0; nt3 < 2; ++nt3)
#pragma unroll
        for (int nt = 0; nt < 4; ++nt) {
            const float4 v = ldg4(w3 + (nt3 * 16 + s) * 64 + nt * 16 + q * 4);
            bf16x4 f;
            f[0]=f2bf(v.x); f[1]=f2bf(v.y); f[2]=f2bf(v.z); f[3]=f2bf(v.w);
            w3f[nt3][nt] = f;
        }
    f32x4 b2i[4];
#pragma unroll
    for (int nt = 0; nt < 4; ++nt) {
        const float4 v = ldg4(b2 + nt * 16 + q * 4);
        b2i[nt] = f32x4{v.x, v.y, v.z, v.w};
    }
    f32x4 b3i[2];
#pragma unroll
    for (int nt3 = 0; nt3 < 2; ++nt3) {
        const float4 v = ldg4(b3 + nt3 * 16 + q * 4);
        b3i[nt3] = f32x4{v.x, v.y, v.z, v.w};
    }

    // wave's store base: combo = cbi*1024 + mt*64 + row, o = nt3*16 + q*4 + r
    float* gbase = out + ((size_t)b * 4096 + (cbi << 10) + row) * 32 + q * 4;

    for (int mhi = 0; mhi < 2; ++mhi) {
        // ap3 = A01[row] + P + Bt3[r3]   (r3 fixed within mhi half)
        const float* bt3 = Bt + (24 + (((cbi << 1) + mhi) & 7)) * 64;
        float ap3[16];
#pragma unroll
        for (int c4 = 0; c4 < 4; ++c4) {
            const int hc = (c4 >> 1) * 32 + q * 8 + (c4 & 1) * 4;
            const f32x4 av = *reinterpret_cast<const f32x4*>(A01 + row * 64 + (hc ^ amask));
            const f32x4 pv = *reinterpret_cast<const f32x4*>(Pt + hc);
            const f32x4 v3 = *reinterpret_cast<const f32x4*>(bt3 + hc);
#pragma unroll
            for (int j = 0; j < 4; ++j) ap3[c4*4+j] = av[j] + pv[j] + v3[j];
        }
#pragma unroll
        for (int mlo = 0; mlo < 8; ++mlo) {
            const float* bt2 = Bt + (16 + mlo) * 64;   // r2 = mt&7 = mlo
            // h1 = relu(ap3 + Bt2), fp32 -> bf16 fragment [n=combo][k=h]
            bf16x8 h1f0, h1f1;
            {
                float tmp[16];
#pragma unroll
                for (int c4 = 0; c4 < 4; ++c4) {
                    const int hc = (c4 >> 1) * 32 + q * 8 + (c4 & 1) * 4;
                    const f32x4 v2 = *reinterpret_cast<const f32x4*>(bt2 + hc);
#pragma unroll
                    for (int j = 0; j < 4; ++j)
                        tmp[c4*4+j] = fmaxf(ap3[c4*4+j] + v2[j], 0.f);
                }
#pragma unroll
                for (int j = 0; j < 8; ++j) h1f0[j] = f2bf(tmp[j]);
#pragma unroll
                for (int j = 0; j < 8; ++j) h1f1[j] = f2bf(tmp[8 + j]);
            }
            // layer 2: D2[m=g][n=combo]
            f32x4 a2[4];
#pragma unroll
            for (int nt = 0; nt < 4; ++nt) {
                f32x4 acc = b2i[nt];
                acc = MFMA_K32(w2f[nt][0], h1f0, acc);
                acc = MFMA_K32(w2f[nt][1], h1f1, acc);
                a2[nt] = acc;
            }
            // relu + cvt: D2 regs are exactly the K=16 B-fragment
            bf16x4 h2f[4];
#pragma unroll
            for (int nt = 0; nt < 4; ++nt) {
                bf16x4 f;
#pragma unroll
                for (int r = 0; r < 4; ++r) f[r] = f2bf(fmaxf(a2[nt][r], 0.f));
                h2f[nt] = f;
            }
            // layer 3 + direct contiguous stores (plain, cached like the fill)
            float* gb = gbase + (mhi * 8 + mlo) * 2048;  // +64 combos per step
#pragma unroll
            for (int nt3 = 0; nt3 < 2; ++nt3) {
                f32x4 acc = b3i[nt3];
#pragma unroll
                for (int nt = 0; nt < 4; ++nt)
                    acc = MFMA_K16(w3f[nt3][nt], h2f[nt], acc);
                *reinterpret_cast<f32x4*>(gb + nt3 * 16) = acc;
            }
        }
    }
}

extern "C" void kernel_launch(void* const* d_in, const int* in_sizes, int n_in,
                              void* d_out, int out_size, void* d_ws, size_t ws_size,
                              hipStream_t stream) {
    const float* phi = (const float*)d_in[0];
    const float* rp  = (const float*)d_in[1];
    const float* w1  = (const float*)d_in[2];
    const float* b1  = (const float*)d_in[3];
    const float* w2  = (const float*)d_in[4];
    const float* b2  = (const float*)d_in[5];
    const float* w3  = (const float*)d_in[6];
    const float* b3  = (const float*)d_in[7];
    (void)in_sizes; (void)n_in; (void)out_size; (void)d_ws; (void)ws_size;

    zdec_kernel<<<dim3(1024), dim3(256), 0, stream>>>(
        phi, rp, w1, b1, w2, b2, w3, b3, (float*)d_out);
}

// Round 7
// 42.284 us; speedup vs baseline: 2.5389x; 2.5389x over previous
//
#include <hip/hip_runtime.h>
#include <hip/hip_bf16.h>

// ZDecoder: qs[b,c,o] = MLP(concat(V(c), phi(b)))
// R6 post-mortem: plain partial-line stores -> read-allocate RMW (FETCH==output
// size). nt suppresses RMW but drains at ~2.5 TB/s (R4/R5). Only plain +
// full-line-per-instruction (the fill) hits 6.6 TB/s.
// R7: R6 skeleton (block = 1 batch x 1024 combos, contiguous ascending 128 KiB
// per block) + per-wave LDS staging of D3 -> 2x 1 KiB fully-contiguous PLAIN
// stores per step (8 full 128-B lines per instruction, no RMW, no nt).

typedef __attribute__((ext_vector_type(8))) short bf16x8;
typedef __attribute__((ext_vector_type(4))) short bf16x4;
typedef __attribute__((ext_vector_type(4))) float f32x4;

#define MFMA_K32(a, b, c) __builtin_amdgcn_mfma_f32_16x16x32_bf16(a, b, c, 0, 0, 0)

#if defined(__has_builtin)
#if __has_builtin(__builtin_amdgcn_mfma_f32_16x16x16bf16_1k)
#define MFMA_K16(a, b, c) __builtin_amdgcn_mfma_f32_16x16x16bf16_1k(a, b, c, 0, 0, 0)
#elif __has_builtin(__builtin_amdgcn_mfma_f32_16x16x16_bf16)
#define MFMA_K16(a, b, c) __builtin_amdgcn_mfma_f32_16x16x16_bf16(a, b, c, 0, 0, 0)
#endif
#endif
#ifndef MFMA_K16
__device__ __forceinline__ f32x4 mfma_k16_asm(bf16x4 a, bf16x4 b, f32x4 c) {
    f32x4 d;
    asm("v_mfma_f32_16x16x16_bf16 %0, %1, %2, %3" : "=v"(d) : "v"(a), "v"(b), "v"(c));
    return d;
}
#define MFMA_K16(a, b, c) mfma_k16_asm(a, b, c)
#endif

__device__ __forceinline__ short f2bf(float x) {
    union { __hip_bfloat16 b; short s; } u;
    u.b = __float2bfloat16(x);
    return u.s;
}

__device__ __forceinline__ float4 ldg4(const float* p) {
    return *reinterpret_cast<const float4*>(p);
}

__global__ __launch_bounds__(256, 4)
void zdec_kernel(const float* __restrict__ phi, const float* __restrict__ rp,
                 const float* __restrict__ w1, const float* __restrict__ b1,
                 const float* __restrict__ w2, const float* __restrict__ b2,
                 const float* __restrict__ w3, const float* __restrict__ b3,
                 float* __restrict__ out)
{
    // 32.25 KiB: A01[4096] | Bt[2048] | Pt[64] | Ot[4][512]
    __shared__ float smem[8256];
    float* const A01 = smem;          // [64 low-combos][64 h], XOR-swizzled
    float* const Bt  = smem + 4096;   // [4 lv][8 rg][64 h]
    float* const Pt  = smem + 6144;   // [64 h] for this block's single batch
    float* const Ot  = smem + 6208;   // per-wave 2 KiB store-staging

    const int t   = threadIdx.x;
    const int b   = blockIdx.x >> 2;  // batch 0..255
    const int cbi = blockIdx.x & 3;   // combo quarter: combos [cbi*1024, +1024)

    // ---------------- setup: B table ----------------
    {
        const int l = t >> 6, h = t & 63;
        float ws[16];
#pragma unroll
        for (int z4 = 0; z4 < 4; ++z4) {
            const float4 v = ldg4(w1 + h * 128 + l * 16 + z4 * 4);
            ws[z4*4+0] = v.x; ws[z4*4+1] = v.y; ws[z4*4+2] = v.z; ws[z4*4+3] = v.w;
        }
#pragma unroll
        for (int r = 0; r < 8; ++r) {
            float acc = 0.f;
#pragma unroll
            for (int z4 = 0; z4 < 4; ++z4) {
                const float4 v = ldg4(rp + (l * 8 + r) * 16 + z4 * 4);
                acc += ws[z4*4+0]*v.x + ws[z4*4+1]*v.y + ws[z4*4+2]*v.z + ws[z4*4+3]*v.w;
            }
            Bt[(l * 8 + r) * 64 + h] = acc;
        }
    }
    // ---------------- setup: P row for this block's batch ----------------
    if (t < 64) {
        const int h = t;
        float acc = b1[h];
#pragma unroll
        for (int p4 = 0; p4 < 16; ++p4) {
            const float4 wv = ldg4(w1 + h * 128 + 64 + p4 * 4);
            const float4 pv = ldg4(phi + b * 64 + p4 * 4);
            acc += wv.x * pv.x + wv.y * pv.y + wv.z * pv.z + wv.w * pv.w;
        }
        Pt[h] = acc;
    }
    __syncthreads();
    // ---------------- setup: A01 = Bt0[r0] + Bt1[r1], swizzled ----------------
    {
        const int h = t & 63, cg = t >> 6;
#pragma unroll
        for (int cc2 = 0; cc2 < 16; ++cc2) {
            const int cc = cg * 16 + cc2;
            A01[cc * 64 + (h ^ ((cc & 15) << 2))] =
                Bt[(cc & 7) * 64 + h] + Bt[(8 + ((cc >> 3) & 7)) * 64 + h];
        }
    }
    __syncthreads();

    // ---------------- main: 16 steps x 64 combos (contiguous ascending) -------
    const int lane = t & 63;
    const int wid  = t >> 6;
    const int q = lane >> 4;         // quarter-wave group
    const int s = lane & 15;
    const int row = (wid << 4) + s;  // lane's low-combo index (fixed all steps)
    const int amask = s << 2;

    // w2 as layer-2 A-operand: A[m=g=nt*16+s][k=h=kt*32+q*8+j]
    bf16x8 w2f[4][2];
#pragma unroll
    for (int nt = 0; nt < 4; ++nt)
#pragma unroll
        for (int kt = 0; kt < 2; ++kt) {
            const float* src = w2 + (nt * 16 + s) * 64 + kt * 32 + q * 8;
            const float4 v0 = ldg4(src), v1 = ldg4(src + 4);
            bf16x8 f;
            f[0]=f2bf(v0.x); f[1]=f2bf(v0.y); f[2]=f2bf(v0.z); f[3]=f2bf(v0.w);
            f[4]=f2bf(v1.x); f[5]=f2bf(v1.y); f[6]=f2bf(v1.z); f[7]=f2bf(v1.w);
            w2f[nt][kt] = f;
        }
    // w3 as layer-3 K=16 A-operand: A[m=o=nt3*16+s][k=g=nt*16+q*4+j]
    bf16x4 w3f[2][4];
#pragma unroll
    for (int nt3 = 0; nt3 < 2; ++nt3)
#pragma unroll
        for (int nt = 0; nt < 4; ++nt) {
            const float4 v = ldg4(w3 + (nt3 * 16 + s) * 64 + nt * 16 + q * 4);
            bf16x4 f;
            f[0]=f2bf(v.x); f[1]=f2bf(v.y); f[2]=f2bf(v.z); f[3]=f2bf(v.w);
            w3f[nt3][nt] = f;
        }
    f32x4 b2i[4];
#pragma unroll
    for (int nt = 0; nt < 4; ++nt) {
        const float4 v = ldg4(b2 + nt * 16 + q * 4);
        b2i[nt] = f32x4{v.x, v.y, v.z, v.w};
    }
    f32x4 b3i[2];
#pragma unroll
    for (int nt3 = 0; nt3 < 2; ++nt3) {
        const float4 v = ldg4(b3 + nt3 * 16 + q * 4);
        b3i[nt3] = f32x4{v.x, v.y, v.z, v.w};
    }

    float* const ot = Ot + (wid << 9);  // this wave's 512-float staging row-block
    // wave's contiguous 2-KiB region per step: combos [cbi*1024 + mt*64 + wid*16, +16)
    float* const gwbase = out + ((size_t)b * 4096 + (cbi << 10) + (wid << 4)) * 32;

    for (int mhi = 0; mhi < 2; ++mhi) {
        // ap3 = A01[row] + P + Bt3[r3]   (r3 fixed within mhi half)
        const float* bt3 = Bt + (24 + (((cbi << 1) + mhi) & 7)) * 64;
        float ap3[16];
#pragma unroll
        for (int c4 = 0; c4 < 4; ++c4) {
            const int hc = (c4 >> 1) * 32 + q * 8 + (c4 & 1) * 4;
            const f32x4 av = *reinterpret_cast<const f32x4*>(A01 + row * 64 + (hc ^ amask));
            const f32x4 pv = *reinterpret_cast<const f32x4*>(Pt + hc);
            const f32x4 v3 = *reinterpret_cast<const f32x4*>(bt3 + hc);
#pragma unroll
            for (int j = 0; j < 4; ++j) ap3[c4*4+j] = av[j] + pv[j] + v3[j];
        }
#pragma unroll
        for (int mlo = 0; mlo < 8; ++mlo) {
            const float* bt2 = Bt + (16 + mlo) * 64;   // r2 = mt&7 = mlo
            // h1 = relu(ap3 + Bt2), fp32 -> bf16 fragment [n=combo][k=h]
            bf16x8 h1f0, h1f1;
            {
                float tmp[16];
#pragma unroll
                for (int c4 = 0; c4 < 4; ++c4) {
                    const int hc = (c4 >> 1) * 32 + q * 8 + (c4 & 1) * 4;
                    const f32x4 v2 = *reinterpret_cast<const f32x4*>(bt2 + hc);
#pragma unroll
                    for (int j = 0; j < 4; ++j)
                        tmp[c4*4+j] = fmaxf(ap3[c4*4+j] + v2[j], 0.f);
                }
#pragma unroll
                for (int j = 0; j < 8; ++j) h1f0[j] = f2bf(tmp[j]);
#pragma unroll
                for (int j = 0; j < 8; ++j) h1f1[j] = f2bf(tmp[8 + j]);
            }
            // layer 2: D2[m=g][n=combo]
            f32x4 a2[4];
#pragma unroll
            for (int nt = 0; nt < 4; ++nt) {
                f32x4 acc = b2i[nt];
                acc = MFMA_K32(w2f[nt][0], h1f0, acc);
                acc = MFMA_K32(w2f[nt][1], h1f1, acc);
                a2[nt] = acc;
            }
            // relu + cvt: D2 regs are exactly the K=16 B-fragment
            bf16x4 h2f[4];
#pragma unroll
            for (int nt = 0; nt < 4; ++nt) {
                bf16x4 f;
#pragma unroll
                for (int r = 0; r < 4; ++r) f[r] = f2bf(fmaxf(a2[nt][r], 0.f));
                h2f[nt] = f;
            }
            // layer 3: D3[m=o][n=combo]; lane holds region[s*32 + (nt3*4+q)*4 ..+4].
            // Stage to Ot (chunk-swizzled), then 2x 1 KiB contiguous PLAIN stores.
#pragma unroll
            for (int nt3 = 0; nt3 < 2; ++nt3) {
                f32x4 acc = b3i[nt3];
#pragma unroll
                for (int nt = 0; nt < 4; ++nt)
                    acc = MFMA_K16(w3f[nt3][nt], h2f[nt], acc);
                const int c = (nt3 * 4 + q) ^ (s & 7);   // chunk swizzle
                *reinterpret_cast<f32x4*>(ot + s * 32 + c * 4) = acc;
            }
            asm volatile("s_waitcnt lgkmcnt(0)" ::: "memory");  // wave-sync staging
            {
                float* gb = gwbase + (mhi * 8 + mlo) * 2048;  // +64 combos per step
#pragma unroll
                for (int k = 0; k < 2; ++k) {
                    const int sr = k * 8 + (lane >> 3);
                    const int cr = (lane & 7) ^ (sr & 7);
                    const f32x4 v = *reinterpret_cast<const f32x4*>(ot + sr * 32 + cr * 4);
                    *reinterpret_cast<f32x4*>(gb + k * 256 + lane * 4) = v;  // plain, full lines
                }
            }
            // WAR on ot across steps safe: same-wave DS ops retire in order.
        }
    }
}

extern "C" void kernel_launch(void* const* d_in, const int* in_sizes, int n_in,
                              void* d_out, int out_size, void* d_ws, size_t ws_size,
                              hipStream_t stream) {
    const float* phi = (const float*)d_in[0];
    const float* rp  = (const float*)d_in[1];
    const float* w1  = (const float*)d_in[2];
    const float* b1  = (const float*)d_in[3];
    const float* w2  = (const float*)d_in[4];
    const float* b2  = (const float*)d_in[5];
    const float* w3  = (const float*)d_in[6];
    const float* b3  = (const float*)d_in[7];
    (void)in_sizes; (void)n_in; (void)out_size; (void)d_ws; (void)ws_size;

    zdec_kernel<<<dim3(1024), dim3(256), 0, stream>>>(
        phi, rp, w1, b1, w2, b2, w3, b3, (float*)d_out);
}